// Round 1
// baseline (628.136 us; speedup 1.0000x reference)
//
#include <hip/hip_runtime.h>
#include <hip/hip_bf16.h>

// Problem constants (from reference setup_inputs)
constexpr int N_NODES = 50000;
constexpr int N_EDGES = 800000;
constexpr int E_TOT   = N_EDGES + N_NODES;   // with self loops
constexpr int F_IN    = 128;
constexpr int F_OUT   = 128;
constexpr int HEADS   = 2;

// ---------------------------------------------------------------------------
// Kernel 1: xw = x @ w   (x: [N,128] f32, w: [128, 256] f32 -> xw: [N, 256])
// One block (256 threads) per node row; x row staged in LDS.
// ---------------------------------------------------------------------------
__global__ void xw_kernel(const float* __restrict__ x,
                          const float* __restrict__ w,
                          float* __restrict__ xw) {
    const int n   = blockIdx.x;
    const int col = threadIdx.x;           // 0..255
    __shared__ float xs[F_IN];
    if (col < F_IN) xs[col] = x[(size_t)n * F_IN + col];
    __syncthreads();
    float acc = 0.f;
#pragma unroll
    for (int k = 0; k < F_IN; ++k) {
        acc = fmaf(xs[k], w[k * (HEADS * F_OUT) + col], acc);
    }
    xw[(size_t)n * (HEADS * F_OUT) + col] = acc;
}

// ---------------------------------------------------------------------------
// Kernel 2: per-edge attention + message, atomic accumulate into out.
// One wave (64 lanes) per edge; 128 features = 2 per lane.
// ---------------------------------------------------------------------------
__global__ void edge_kernel(const float* __restrict__ x,
                            const int*   __restrict__ ei,   // [2, N_EDGES] flat
                            const float* __restrict__ u,    // [128, 2]
                            const float* __restrict__ c,    // [2]
                            const float* __restrict__ xw,   // [N, 2, 128]
                            float* __restrict__ out,        // [N, 128] accum
                            int*   __restrict__ cnt) {
    const int wave_in_blk = threadIdx.x >> 6;
    const int lane        = threadIdx.x & 63;
    const long e = (long)blockIdx.x * (blockDim.x >> 6) + wave_in_blk;
    if (e >= E_TOT) return;

    int src, dst;
    if (e < N_EDGES) {
        src = ei[e];
        dst = ei[N_EDGES + e];
    } else {
        src = dst = (int)(e - N_EDGES);   // self loop
    }

    const float* xs = x + (size_t)src * F_IN;
    const float* xd = x + (size_t)dst * F_IN;

    // (x_j - x_i) for this lane's two features
    const float d0 = xs[lane]      - xd[lane];
    const float d1 = xs[lane + 64] - xd[lane + 64];

    // partial dot with u[:,0] and u[:,1]  (u row-major [128,2])
    float p0 = d0 * u[lane * 2 + 0]      + d1 * u[(lane + 64) * 2 + 0];
    float p1 = d0 * u[lane * 2 + 1]      + d1 * u[(lane + 64) * 2 + 1];

    // wave-wide butterfly reduce (all lanes end with the sum)
#pragma unroll
    for (int off = 1; off < 64; off <<= 1) {
        p0 += __shfl_xor(p0, off, 64);
        p1 += __shfl_xor(p1, off, 64);
    }

    p0 += c[0];
    p1 += c[1];

    // 2-way softmax
    const float m  = fmaxf(p0, p1);
    const float e0 = __expf(p0 - m);
    const float e1 = __expf(p1 - m);
    const float inv = 1.0f / (e0 + e1);
    const float q0 = e0 * inv;
    const float q1 = e1 * inv;

    // message = q0 * xw[src, 0, :] + q1 * xw[src, 1, :]
    const float* xwr = xw + (size_t)src * (HEADS * F_OUT);
    const float m0 = q0 * xwr[lane]            + q1 * xwr[F_OUT + lane];
    const float m1 = q0 * xwr[lane + 64]       + q1 * xwr[F_OUT + lane + 64];

    float* orow = out + (size_t)dst * F_OUT;
    atomicAdd(&orow[lane],      m0);
    atomicAdd(&orow[lane + 64], m1);
    if (lane == 0) atomicAdd(&cnt[dst], 1);
}

// ---------------------------------------------------------------------------
// Kernel 3: out = x + relu(out / max(cnt,1) + bias)
// ---------------------------------------------------------------------------
__global__ void final_kernel(const float* __restrict__ x,
                             const float* __restrict__ bias,
                             const int*   __restrict__ cnt,
                             float* __restrict__ out) {
    const long i = (long)blockIdx.x * blockDim.x + threadIdx.x;
    if (i >= (long)N_NODES * F_OUT) return;
    const int n = (int)(i >> 7);     // /128
    const int f = (int)(i & 127);
    const float inv = 1.0f / (float)max(cnt[n], 1);
    const float a = out[i] * inv + bias[f];
    out[i] = x[i] + fmaxf(a, 0.0f);
}

// ---------------------------------------------------------------------------
extern "C" void kernel_launch(void* const* d_in, const int* in_sizes, int n_in,
                              void* d_out, int out_size, void* d_ws, size_t ws_size,
                              hipStream_t stream) {
    const float* x    = (const float*)d_in[0];
    const int*   ei   = (const int*)  d_in[1];   // [2, N_EDGES] flat int32
    const float* u    = (const float*)d_in[2];
    const float* c    = (const float*)d_in[3];
    const float* w    = (const float*)d_in[4];
    const float* bias = (const float*)d_in[5];
    float* out = (float*)d_out;

    // workspace layout: xw [N*256 f32] | cnt [N int32]
    float* xw  = (float*)d_ws;
    int*   cnt = (int*)((char*)d_ws + (size_t)N_NODES * (HEADS * F_OUT) * sizeof(float));

    // zero the accumulators (we accumulate via atomics every call)
    hipMemsetAsync(d_out, 0, (size_t)out_size * sizeof(float), stream);
    hipMemsetAsync(cnt, 0, (size_t)N_NODES * sizeof(int), stream);

    // 1) xw = x @ w
    xw_kernel<<<N_NODES, 256, 0, stream>>>(x, w, xw);

    // 2) per-edge attention + atomic aggregate (1 wave per edge, 4 waves/block)
    const int edges_per_block = 4;
    const int eg = (E_TOT + edges_per_block - 1) / edges_per_block;
    edge_kernel<<<eg, 256, 0, stream>>>(x, ei, u, c, xw, out, cnt);

    // 3) finalize: mean, +bias, relu, +x
    const long tot = (long)N_NODES * F_OUT;
    final_kernel<<<(int)((tot + 255) / 256), 256, 0, stream>>>(x, bias, cnt, out);
}